// Round 11
// baseline (78.770 us; speedup 1.0000x reference)
//
#include <hip/hip_runtime.h>
#include <hip/hip_bf16.h>
#include <stdint.h>

#define NQ 14
#define DIM 16384
#define NL 6
#define NBATCH 1024
#define PI_F 3.14159265358979323846f
#define BLOCK 256

// ================= constexpr GF(2) circuit algebra =================
// Verified end-to-end (rounds 2/5/7 absmax 0.0; round 10 bf16 absmax 3.9e-3).
// CNOT chain = I+S.  After l chains, gate on bit p pairs i with i^mcol(l,p);
// side-0 selected by parity(i & grow(l,p)).  Lucas: C(l,k) odd iff (k&~l)==0.
constexpr uint32_t mcol(int l, int p) {          // column p of (I+S)^l
    uint32_t m = 0;
    for (int k = 0; k <= p; ++k) if ((k & ~l) == 0) m ^= 1u << (p - k);
    return m;
}
constexpr uint32_t grow(int l, int p) {          // row p of U^l = (I+S)^(16-l)
    uint32_t g = 0;
    const int e = 16 - l;
    for (int k = 0; k + p < NQ; ++k) if ((k & ~e) == 0) g ^= 1u << (p + k);
    return g;
}
constexpr uint32_t popb(uint32_t x) { uint32_t c = 0; while (x) { c += x & 1u; x >>= 1; } return c; }
constexpr int msbit(uint32_t m) { int b = 0; while (m >> (b + 1)) ++b; return b; }
// Bank swizzle on ELEMENT index (bf16: u32 addr = elem>>1, banks = elem bits 1..5).
// Fold elem bits 6..8 -> 2..4 and bit 9 -> 5.  XOR-linear, bijective
// (triangular), preserves low-2 bits (quad structure intact).
constexpr uint32_t PB(uint32_t x) {
    return x ^ (((x >> 6) & 7u) << 2) ^ (((x >> 9) & 1u) << 5);
}

// 3 groups per layer (round-5 structure): p ranges {0..5}, {6..9}, {10..13}
template<int GRP> constexpr int pbase()  { return GRP == 0 ? 0 : (GRP == 1 ? 6 : 10); }
template<int GRP> constexpr int ngates() { return GRP == 0 ? 6 : 4; }

// phase basis: {e0,e1} + 4 hi vectors (4-aligned)
template<int L, int GRP, int J> constexpr uint32_t mhv() {
    if constexpr (GRP == 0) return 4u << J;                       // e2..e5
    else return mcol(L, pbase<GRP>() + J) & ~3u;                  // gate hi parts
}
template<int L, int GRP, int K> constexpr uint32_t rmv() {        // register-space mask
    if constexpr (GRP == 0) return mcol(L, K);                    // identity basis
    else return (4u << K) | (mcol(L, pbase<GRP>() + K) & 3u);
}
constexpr uint32_t mreg(uint32_t r, uint32_t m0, uint32_t m1, uint32_t m2, uint32_t m3) {
    uint32_t M = r & 3u;
    if (r & 4u)  M ^= m0;
    if (r & 8u)  M ^= m1;
    if (r & 16u) M ^= m2;
    if (r & 32u) M ^= m3;
    return M;
}
constexpr uint64_t sgnw_f(uint32_t m0, uint32_t m1, uint32_t m2, uint32_t m3, uint32_t g) {
    uint64_t w = 0;
    for (uint32_t r = 0; r < 64; ++r)
        w |= (uint64_t)(popb(mreg(r, m0, m1, m2, m3) & g) & 1u) << r;
    return w;
}
template<int GRP> constexpr uint32_t cg_of(uint32_t g) {          // tid-parity mask
    if constexpr (GRP == 0) return (g >> 6) & 0xFFu;                              // comp = e6..e13
    else if constexpr (GRP == 1) return ((g >> 2) & 0xFu) | (((g >> 10) & 0xFu) << 4); // e2..e5,e10..e13
    else return (g >> 2) & 0xFFu;                                                 // e2..e9
}
constexpr bool indep6(uint32_t a, uint32_t b, uint32_t c, uint32_t d) {
    uint32_t v[6] = {1u, 2u, a, b, c, d};
    int rank = 0;
    for (int bit = 13; bit >= 0; --bit) {
        int piv = -1;
        for (int i = rank; i < 6; ++i) if ((v[i] >> bit) & 1) { piv = i; break; }
        if (piv < 0) continue;
        uint32_t t = v[piv]; v[piv] = v[rank]; v[rank] = t;
        for (int i = 0; i < 6; ++i) if (i != rank && ((v[i] >> bit) & 1)) v[i] ^= t;
        ++rank;
    }
    return rank == 6;
}

// RAW thread-base element index (un-swizzled); 8 tid bits -> comp unit bits
template<int GRP> __device__ __forceinline__ uint32_t tb_of(uint32_t tid) {
    if constexpr (GRP == 0)      return tid << 6;
    else if constexpr (GRP == 1) return ((tid & 15u) << 2) | ((tid & 0xF0u) << 6);
    else                         return tid << 2;
}

// ================= bf16 pack/unpack (state transit precision) =================
// pack: __float22bfloat162_rn -> v_cvt_pk_bf16_f32 (RNE, unbiased; compiler
// intrinsic, not inline asm — m240: asm cvt_pk hurts scheduling).
// unpack: exact (bf16 -> f32 lossless via bit ops).
__device__ __forceinline__ uint32_t pk2c(float lo, float hi) {
    __hip_bfloat162 h = __float22bfloat162_rn(float2{lo, hi});
    union { __hip_bfloat162 h2; uint32_t u; } cv;
    cv.h2 = h;
    return cv.u;
}
__device__ __forceinline__ void unpk2(uint32_t u, float& lo, float& hi) {
    lo = __uint_as_float(u << 16);
    hi = __uint_as_float(u & 0xffff0000u);
}

// ================= register-space gate (all compile-time) =================
template<uint32_t RM, uint64_t SG>
__device__ __forceinline__ void gate64(float (&rs)[64], float c, float svp) {
    constexpr uint32_t HB = 1u << msbit(RM);
#pragma unroll
    for (uint32_t r = 0; r < 64; ++r) {
        if ((r & HB) == 0u) {
            const float sv = ((SG >> r) & 1ull) ? -svp : svp;   // compile-time select
            const float u = rs[r], v = rs[r ^ RM];
            const float t0 = sv * v;
            const float t1 = sv * u;
            rs[r]      = fmaf(c, u, -t0);   // side0' = c*s0 - s*s1
            rs[r ^ RM] = fmaf(c, v,  t1);   // side1' = c*s1 + s*s0
        }
    }
}

template<int L, int GRP, int K>
__device__ __forceinline__ void gates_rec(float (&rs)[64], const float* __restrict__ cst,
                                          const float* __restrict__ snt, int tid) {
    if constexpr (K < ngates<GRP>()) {
        constexpr int p = pbase<GRP>() + K;
        constexpr uint32_t g  = grow(L, p);
        constexpr uint32_t RM = rmv<L, GRP, K>();
        constexpr uint64_t SG = sgnw_f(mhv<L,GRP,0>(), mhv<L,GRP,1>(), mhv<L,GRP,2>(), mhv<L,GRP,3>(), g);
        constexpr uint32_t CG = cg_of<GRP>(g);
        constexpr int widx = (L - 1) * NQ + (13 - p);
        const float c = cst[widx];
        const float s = snt[widx];
        const float svp = (__popc((uint32_t)tid & CG) & 1) ? -s : s;
        gate64<RM, SG>(rs, c, svp);
        gates_rec<L, GRP, K + 1>(rs, cst, snt, tid);
    }
}

template<int L, int GRP>
__device__ __forceinline__ void run_gates(float (&rs)[64], const float* __restrict__ cst,
                                          const float* __restrict__ snt, int tid) {
    static_assert(indep6(mhv<L,GRP,0>(), mhv<L,GRP,1>(), mhv<L,GRP,2>(), mhv<L,GRP,3>()), "basis rank");
    gates_rec<L, GRP, 0>(rs, cst, snt, tid);
}

// LDS IO: 16 quads x (2 x bf16x2 = uint2, 8B).  u32 addr = PB(elem)>>1 (even).
template<int L, int GRP, bool WR>
__device__ __forceinline__ void lds_io(float (&rs)[64], uint32_t* st, int tid) {
    constexpr uint32_t m0 = mhv<L,GRP,0>(), m1 = mhv<L,GRP,1>(), m2 = mhv<L,GRP,2>(), m3 = mhv<L,GRP,3>();
    const uint32_t ptw = PB(tb_of<GRP>((uint32_t)tid));
#pragma unroll
    for (uint32_t gq = 0; gq < 16; ++gq) {
        const uint32_t K = ((gq & 1) ? m0 : 0u) ^ ((gq & 2) ? m1 : 0u) ^
                           ((gq & 4) ? m2 : 0u) ^ ((gq & 8) ? m3 : 0u);
        const uint32_t a = (ptw ^ PB(K)) >> 1;        // PB(K) folds (PB is XOR-linear)
        if constexpr (WR) {
            uint2 v;
            v.x = pk2c(rs[gq * 4 + 0], rs[gq * 4 + 1]);
            v.y = pk2c(rs[gq * 4 + 2], rs[gq * 4 + 3]);
            *reinterpret_cast<uint2*>(st + a) = v;
        } else {
            const uint2 v = *reinterpret_cast<const uint2*>(st + a);
            unpk2(v.x, rs[gq * 4 + 0], rs[gq * 4 + 1]);
            unpk2(v.y, rs[gq * 4 + 2], rs[gq * 4 + 3]);
        }
    }
}

template<int L, int GRP>
__device__ __forceinline__ void mid_phase(float (&rs)[64], uint32_t* st,
        const float* __restrict__ cst, const float* __restrict__ snt, int tid) {
    lds_io<L, GRP, false>(rs, st, tid);
    run_gates<L, GRP>(rs, cst, snt, tid);
    lds_io<L, GRP, true>(rs, st, tid);
    __syncthreads();
}

// ================= prepass: min/scale + gate cos/sin tables =================
__global__ __launch_bounds__(256) void qs_norm_kernel(const float* __restrict__ x,
                                                      const float* __restrict__ w,
                                                      float* __restrict__ ws) {
    const int q = blockIdx.x;
    const int tid = threadIdx.x;
    float mn = 3.0e38f, mx = -3.0e38f;
    for (int r = tid; r < NBATCH; r += 256) {
        const float v = x[r * NQ + q];
        mn = fminf(mn, v);
        mx = fmaxf(mx, v);
    }
#pragma unroll
    for (int off = 32; off > 0; off >>= 1) {
        mn = fminf(mn, __shfl_down(mn, off));
        mx = fmaxf(mx, __shfl_down(mx, off));
    }
    __shared__ float smn[4], smx[4];
    const int wid = tid >> 6, lane = tid & 63;
    if (lane == 0) { smn[wid] = mn; smx[wid] = mx; }
    __syncthreads();
    if (tid == 0) {
        mn = fminf(fminf(smn[0], smn[1]), fminf(smn[2], smn[3]));
        mx = fmaxf(fmaxf(smx[0], smx[1]), fmaxf(smx[2], smx[3]));
        ws[q] = mn;
        ws[NQ + q] = PI_F / (mx - mn + 1e-8f);
    }
    if (blockIdx.x == 0) {
        for (int t = tid; t < (NL - 1) * NQ; t += 256) {
            const float h = 0.5f * w[NQ + t];
            ws[32 + t]  = cosf(h);
            ws[112 + t] = sinf(h);
        }
    }
}

// ================= main: one block (256 threads) per batch element =================
__global__ __launch_bounds__(BLOCK, 4) void qs_main_kernel(
        const float* __restrict__ x, const float* __restrict__ w,
        const float* __restrict__ nrm, const float* __restrict__ cst,
        const float* __restrict__ snt, float* __restrict__ out) {
    __shared__ __align__(16) uint32_t st[DIM / 2];    // 32 KB bf16 state
    __shared__ float sciL[NQ], ssiL[NQ];
    __shared__ float red0[4], red1[4];
    const int tid = threadIdx.x;
    const int b = blockIdx.x;

    // merged encoding + layer-0 angles, once per block (broadcast via LDS)
    if (tid < NQ) {
        const float ang = (x[b * NQ + tid] - nrm[tid]) * nrm[NQ + tid] + w[tid];
        const float h = 0.5f * ang;
        sciL[tid] = cosf(h);
        ssiL[tid] = sinf(h);
    }
    __syncthreads();

    // product state directly in registers, layout (1,0): i=(tid<<6)|r, bit b <-> qubit 13-b
    float H = 1.0f;
#pragma unroll
    for (int q = 0; q < 8; ++q) H *= ((tid >> (7 - q)) & 1) ? ssiL[q] : sciL[q];
    float p2[4], p4[16], hh[4];
#pragma unroll
    for (int j = 0; j < 4; ++j) p2[j] = ((j & 1) ? ssiL[13] : sciL[13]) * ((j & 2) ? ssiL[12] : sciL[12]);
#pragma unroll
    for (int j = 0; j < 16; ++j) p4[j] = p2[j & 3] * ((j & 4) ? ssiL[11] : sciL[11]) * ((j & 8) ? ssiL[10] : sciL[10]);
#pragma unroll
    for (int j = 0; j < 4; ++j) hh[j] = H * ((j & 1) ? ssiL[9] : sciL[9]) * ((j & 2) ? ssiL[8] : sciL[8]);
    alignas(16) float rs[64];
#pragma unroll
    for (int r = 0; r < 64; ++r) rs[r] = p4[r & 15] * hh[r >> 4];

    // 15 phases, 3 per layer; first has no read, last has no write
    run_gates<1, 0>(rs, cst, snt, tid); lds_io<1, 0, true>(rs, st, tid); __syncthreads();
    mid_phase<1, 1>(rs, st, cst, snt, tid);
    mid_phase<1, 2>(rs, st, cst, snt, tid);
    mid_phase<2, 0>(rs, st, cst, snt, tid);
    mid_phase<2, 1>(rs, st, cst, snt, tid);
    mid_phase<2, 2>(rs, st, cst, snt, tid);
    mid_phase<3, 0>(rs, st, cst, snt, tid);
    mid_phase<3, 1>(rs, st, cst, snt, tid);
    mid_phase<3, 2>(rs, st, cst, snt, tid);
    mid_phase<4, 0>(rs, st, cst, snt, tid);
    mid_phase<4, 1>(rs, st, cst, snt, tid);
    mid_phase<4, 2>(rs, st, cst, snt, tid);
    mid_phase<5, 0>(rs, st, cst, snt, tid);
    mid_phase<5, 1>(rs, st, cst, snt, tid);
    lds_io<5, 2, false>(rs, st, tid);
    run_gates<5, 2>(rs, cst, snt, tid);

    // expectations in-register: gout = e13/e12 (rows 13/12 of U^6);
    // layout (5,2) thread-base has no bits >=10 -> sign compile-time per register
    constexpr uint32_t f0 = mhv<5,2,0>(), f1 = mhv<5,2,1>(), f2 = mhv<5,2,2>(), f3 = mhv<5,2,3>();
    float e0 = 0.0f, e1 = 0.0f;
#pragma unroll
    for (uint32_t r = 0; r < 64; ++r) {
        const uint32_t M = mreg(r, f0, f1, f2, f3);
        const float v = rs[r];
        e0 = fmaf(v, ((M >> 13) & 1u) ? -v : v, e0);
        e1 = fmaf(v, ((M >> 12) & 1u) ? -v : v, e1);
    }
#pragma unroll
    for (int off = 32; off > 0; off >>= 1) {
        e0 += __shfl_down(e0, off);
        e1 += __shfl_down(e1, off);
    }
    const int wid = tid >> 6, lane = tid & 63;
    if (lane == 0) { red0[wid] = e0; red1[wid] = e1; }
    __syncthreads();
    if (tid == 0) {
        out[b * 2 + 0] = red0[0] + red0[1] + red0[2] + red0[3];
        out[b * 2 + 1] = red1[0] + red1[1] + red1[2] + red1[3];
    }
}

extern "C" void kernel_launch(void* const* d_in, const int* in_sizes, int n_in,
                              void* d_out, int out_size, void* d_ws, size_t ws_size,
                              hipStream_t stream) {
    const float* x = (const float*)d_in[0];   // (1024, 14) f32
    const float* w = (const float*)d_in[1];   // (6, 14) f32
    float* out = (float*)d_out;               // (1024, 2) f32
    float* ws = (float*)d_ws;                 // [0..27] min/scale, [32..101] cos, [112..181] sin

    qs_norm_kernel<<<NQ, 256, 0, stream>>>(x, w, ws);
    qs_main_kernel<<<NBATCH, BLOCK, 0, stream>>>(x, w, ws, ws + 32, ws + 112, out);
}

// Round 12
// 70.683 us; speedup vs baseline: 1.1144x; 1.1144x over previous
//
#include <hip/hip_runtime.h>
#include <hip/hip_bf16.h>
#include <stdint.h>

#define NQ 14
#define DIM 16384
#define NL 6
#define NBATCH 1024
#define PI_F 3.14159265358979323846f
#define BLOCK 256

// ================= constexpr GF(2) circuit algebra =================
// Verified end-to-end (rounds 2/5/7 absmax 0.0; rounds 10/11 bf16 absmax 3.9e-3).
// CNOT chain = I+S.  After l chains, gate on bit p pairs i with i^mcol(l,p);
// side-0 selected by parity(i & grow(l,p)).  Lucas: C(l,k) odd iff (k&~l)==0.
constexpr uint32_t mcol(int l, int p) {          // column p of (I+S)^l
    uint32_t m = 0;
    for (int k = 0; k <= p; ++k) if ((k & ~l) == 0) m ^= 1u << (p - k);
    return m;
}
constexpr uint32_t grow(int l, int p) {          // row p of U^l = (I+S)^(16-l)
    uint32_t g = 0;
    const int e = 16 - l;
    for (int k = 0; k + p < NQ; ++k) if ((k & ~e) == 0) g ^= 1u << (p + k);
    return g;
}
constexpr uint32_t popb(uint32_t x) { uint32_t c = 0; while (x) { c += x & 1u; x >>= 1; } return c; }
constexpr int msbit(uint32_t m) { int b = 0; while (m >> (b + 1)) ++b; return b; }
// Bank swizzle on ELEMENT index (bf16: u32 addr = elem>>1, banks = elem bits 1..5).
// Fold elem bits 6..8 -> 2..4 and bit 9 -> 5.  XOR-linear, bijective
// (triangular), preserves low-2 bits (quad structure intact).
// Measured round 11: SQ_LDS_BANK_CONFLICT 5.2e5 (lowest of all structures).
constexpr uint32_t PB(uint32_t x) {
    return x ^ (((x >> 6) & 7u) << 2) ^ (((x >> 9) & 1u) << 5);
}

// 3 groups per layer (round-5 structure): p ranges {0..5}, {6..9}, {10..13}
template<int GRP> constexpr int pbase()  { return GRP == 0 ? 0 : (GRP == 1 ? 6 : 10); }
template<int GRP> constexpr int ngates() { return GRP == 0 ? 6 : 4; }

// phase basis: {e0,e1} + 4 hi vectors (4-aligned)
template<int L, int GRP, int J> constexpr uint32_t mhv() {
    if constexpr (GRP == 0) return 4u << J;                       // e2..e5
    else return mcol(L, pbase<GRP>() + J) & ~3u;                  // gate hi parts
}
template<int L, int GRP, int K> constexpr uint32_t rmv() {        // register-space mask
    if constexpr (GRP == 0) return mcol(L, K);                    // identity basis
    else return (4u << K) | (mcol(L, pbase<GRP>() + K) & 3u);
}
constexpr uint32_t mreg(uint32_t r, uint32_t m0, uint32_t m1, uint32_t m2, uint32_t m3) {
    uint32_t M = r & 3u;
    if (r & 4u)  M ^= m0;
    if (r & 8u)  M ^= m1;
    if (r & 16u) M ^= m2;
    if (r & 32u) M ^= m3;
    return M;
}
constexpr uint64_t sgnw_f(uint32_t m0, uint32_t m1, uint32_t m2, uint32_t m3, uint32_t g) {
    uint64_t w = 0;
    for (uint32_t r = 0; r < 64; ++r)
        w |= (uint64_t)(popb(mreg(r, m0, m1, m2, m3) & g) & 1u) << r;
    return w;
}
template<int GRP> constexpr uint32_t cg_of(uint32_t g) {          // tid-parity mask
    if constexpr (GRP == 0) return (g >> 6) & 0xFFu;                              // comp = e6..e13
    else if constexpr (GRP == 1) return ((g >> 2) & 0xFu) | (((g >> 10) & 0xFu) << 4); // e2..e5,e10..e13
    else return (g >> 2) & 0xFFu;                                                 // e2..e9
}
constexpr bool indep6(uint32_t a, uint32_t b, uint32_t c, uint32_t d) {
    uint32_t v[6] = {1u, 2u, a, b, c, d};
    int rank = 0;
    for (int bit = 13; bit >= 0; --bit) {
        int piv = -1;
        for (int i = rank; i < 6; ++i) if ((v[i] >> bit) & 1) { piv = i; break; }
        if (piv < 0) continue;
        uint32_t t = v[piv]; v[piv] = v[rank]; v[rank] = t;
        for (int i = 0; i < 6; ++i) if (i != rank && ((v[i] >> bit) & 1)) v[i] ^= t;
        ++rank;
    }
    return rank == 6;
}

// RAW thread-base element index (un-swizzled); 8 tid bits -> comp unit bits
template<int GRP> __device__ __forceinline__ uint32_t tb_of(uint32_t tid) {
    if constexpr (GRP == 0)      return tid << 6;
    else if constexpr (GRP == 1) return ((tid & 15u) << 2) | ((tid & 0xF0u) << 6);
    else                         return tid << 2;
}

// ================= bf16 pack/unpack (state transit precision) =================
// pack: __float22bfloat162_rn -> v_cvt_pk_bf16_f32 (RNE, unbiased; compiler
// intrinsic, not inline asm — m240: asm cvt_pk hurts scheduling).
// unpack: exact (bf16 -> f32 lossless via bit ops).
__device__ __forceinline__ uint32_t pk2c(float lo, float hi) {
    __hip_bfloat162 h = __float22bfloat162_rn(float2{lo, hi});
    union { __hip_bfloat162 h2; uint32_t u; } cv;
    cv.h2 = h;
    return cv.u;
}
__device__ __forceinline__ void unpk2(uint32_t u, float& lo, float& hi) {
    lo = __uint_as_float(u << 16);
    hi = __uint_as_float(u & 0xffff0000u);
}

// ================= register-space gate (all compile-time) =================
template<uint32_t RM, uint64_t SG>
__device__ __forceinline__ void gate64(float (&rs)[64], float c, float svp) {
    constexpr uint32_t HB = 1u << msbit(RM);
#pragma unroll
    for (uint32_t r = 0; r < 64; ++r) {
        if ((r & HB) == 0u) {
            const float sv = ((SG >> r) & 1ull) ? -svp : svp;   // compile-time select
            const float u = rs[r], v = rs[r ^ RM];
            const float t0 = sv * v;
            const float t1 = sv * u;
            rs[r]      = fmaf(c, u, -t0);   // side0' = c*s0 - s*s1
            rs[r ^ RM] = fmaf(c, v,  t1);   // side1' = c*s1 + s*s0
        }
    }
}

template<int L, int GRP, int K>
__device__ __forceinline__ void gates_rec(float (&rs)[64], const float* __restrict__ cst,
                                          const float* __restrict__ snt, int tid) {
    if constexpr (K < ngates<GRP>()) {
        constexpr int p = pbase<GRP>() + K;
        constexpr uint32_t g  = grow(L, p);
        constexpr uint32_t RM = rmv<L, GRP, K>();
        constexpr uint64_t SG = sgnw_f(mhv<L,GRP,0>(), mhv<L,GRP,1>(), mhv<L,GRP,2>(), mhv<L,GRP,3>(), g);
        constexpr uint32_t CG = cg_of<GRP>(g);
        constexpr int widx = (L - 1) * NQ + (13 - p);
        const float c = cst[widx];
        const float s = snt[widx];
        const float svp = (__popc((uint32_t)tid & CG) & 1) ? -s : s;
        gate64<RM, SG>(rs, c, svp);
        gates_rec<L, GRP, K + 1>(rs, cst, snt, tid);
    }
}

template<int L, int GRP>
__device__ __forceinline__ void run_gates(float (&rs)[64], const float* __restrict__ cst,
                                          const float* __restrict__ snt, int tid) {
    static_assert(indep6(mhv<L,GRP,0>(), mhv<L,GRP,1>(), mhv<L,GRP,2>(), mhv<L,GRP,3>()), "basis rank");
    gates_rec<L, GRP, 0>(rs, cst, snt, tid);
}

// LDS IO: 16 quads x (2 x bf16x2 = uint2, 8B).  u32 addr = PB(elem)>>1 (even).
template<int L, int GRP, bool WR>
__device__ __forceinline__ void lds_io(float (&rs)[64], uint32_t* st, int tid) {
    constexpr uint32_t m0 = mhv<L,GRP,0>(), m1 = mhv<L,GRP,1>(), m2 = mhv<L,GRP,2>(), m3 = mhv<L,GRP,3>();
    const uint32_t ptw = PB(tb_of<GRP>((uint32_t)tid));
#pragma unroll
    for (uint32_t gq = 0; gq < 16; ++gq) {
        const uint32_t K = ((gq & 1) ? m0 : 0u) ^ ((gq & 2) ? m1 : 0u) ^
                           ((gq & 4) ? m2 : 0u) ^ ((gq & 8) ? m3 : 0u);
        const uint32_t a = (ptw ^ PB(K)) >> 1;        // PB(K) folds (PB is XOR-linear)
        if constexpr (WR) {
            uint2 v;
            v.x = pk2c(rs[gq * 4 + 0], rs[gq * 4 + 1]);
            v.y = pk2c(rs[gq * 4 + 2], rs[gq * 4 + 3]);
            *reinterpret_cast<uint2*>(st + a) = v;
        } else {
            const uint2 v = *reinterpret_cast<const uint2*>(st + a);
            unpk2(v.x, rs[gq * 4 + 0], rs[gq * 4 + 1]);
            unpk2(v.y, rs[gq * 4 + 2], rs[gq * 4 + 3]);
        }
    }
}

template<int L, int GRP>
__device__ __forceinline__ void mid_phase(float (&rs)[64], uint32_t* st,
        const float* __restrict__ cst, const float* __restrict__ snt, int tid) {
    lds_io<L, GRP, false>(rs, st, tid);
    run_gates<L, GRP>(rs, cst, snt, tid);
    lds_io<L, GRP, true>(rs, st, tid);
    __syncthreads();
}

// ================= prepass: min/scale + gate cos/sin tables =================
__global__ __launch_bounds__(256) void qs_norm_kernel(const float* __restrict__ x,
                                                      const float* __restrict__ w,
                                                      float* __restrict__ ws) {
    const int q = blockIdx.x;
    const int tid = threadIdx.x;
    float mn = 3.0e38f, mx = -3.0e38f;
    for (int r = tid; r < NBATCH; r += 256) {
        const float v = x[r * NQ + q];
        mn = fminf(mn, v);
        mx = fmaxf(mx, v);
    }
#pragma unroll
    for (int off = 32; off > 0; off >>= 1) {
        mn = fminf(mn, __shfl_down(mn, off));
        mx = fmaxf(mx, __shfl_down(mx, off));
    }
    __shared__ float smn[4], smx[4];
    const int wid = tid >> 6, lane = tid & 63;
    if (lane == 0) { smn[wid] = mn; smx[wid] = mx; }
    __syncthreads();
    if (tid == 0) {
        mn = fminf(fminf(smn[0], smn[1]), fminf(smn[2], smn[3]));
        mx = fmaxf(fmaxf(smx[0], smx[1]), fmaxf(smx[2], smx[3]));
        ws[q] = mn;
        ws[NQ + q] = PI_F / (mx - mn + 1e-8f);
    }
    if (blockIdx.x == 0) {
        for (int t = tid; t < (NL - 1) * NQ; t += 256) {
            const float h = 0.5f * w[NQ + t];
            ws[32 + t]  = cosf(h);
            ws[112 + t] = sinf(h);
        }
    }
}

// ================= main: one block (256 threads) per batch element =================
// NOTE: no min-waves arg in __launch_bounds__ — rounds 10/11 showed the hint
// caps VGPR at half the computed budget (32/64), spilling rs[] (AGPR-shuffle
// VALU bloat in r10, 53 MB/dispatch scratch HBM in r11). Round 5's plain
// __launch_bounds__(256) allocated 88 VGPR with zero spill.
__global__ __launch_bounds__(BLOCK) void qs_main_kernel(
        const float* __restrict__ x, const float* __restrict__ w,
        const float* __restrict__ nrm, const float* __restrict__ cst,
        const float* __restrict__ snt, float* __restrict__ out) {
    __shared__ __align__(16) uint32_t st[DIM / 2];    // 32 KB bf16 state
    __shared__ float sciL[NQ], ssiL[NQ];
    __shared__ float red0[4], red1[4];
    const int tid = threadIdx.x;
    const int b = blockIdx.x;

    // merged encoding + layer-0 angles, once per block (broadcast via LDS)
    if (tid < NQ) {
        const float ang = (x[b * NQ + tid] - nrm[tid]) * nrm[NQ + tid] + w[tid];
        const float h = 0.5f * ang;
        sciL[tid] = cosf(h);
        ssiL[tid] = sinf(h);
    }
    __syncthreads();

    // product state directly in registers, layout (1,0): i=(tid<<6)|r, bit b <-> qubit 13-b
    float H = 1.0f;
#pragma unroll
    for (int q = 0; q < 8; ++q) H *= ((tid >> (7 - q)) & 1) ? ssiL[q] : sciL[q];
    float p2[4], p4[16], hh[4];
#pragma unroll
    for (int j = 0; j < 4; ++j) p2[j] = ((j & 1) ? ssiL[13] : sciL[13]) * ((j & 2) ? ssiL[12] : sciL[12]);
#pragma unroll
    for (int j = 0; j < 16; ++j) p4[j] = p2[j & 3] * ((j & 4) ? ssiL[11] : sciL[11]) * ((j & 8) ? ssiL[10] : sciL[10]);
#pragma unroll
    for (int j = 0; j < 4; ++j) hh[j] = H * ((j & 1) ? ssiL[9] : sciL[9]) * ((j & 2) ? ssiL[8] : sciL[8]);
    alignas(16) float rs[64];
#pragma unroll
    for (int r = 0; r < 64; ++r) rs[r] = p4[r & 15] * hh[r >> 4];

    // 15 phases, 3 per layer; first has no read, last has no write
    run_gates<1, 0>(rs, cst, snt, tid); lds_io<1, 0, true>(rs, st, tid); __syncthreads();
    mid_phase<1, 1>(rs, st, cst, snt, tid);
    mid_phase<1, 2>(rs, st, cst, snt, tid);
    mid_phase<2, 0>(rs, st, cst, snt, tid);
    mid_phase<2, 1>(rs, st, cst, snt, tid);
    mid_phase<2, 2>(rs, st, cst, snt, tid);
    mid_phase<3, 0>(rs, st, cst, snt, tid);
    mid_phase<3, 1>(rs, st, cst, snt, tid);
    mid_phase<3, 2>(rs, st, cst, snt, tid);
    mid_phase<4, 0>(rs, st, cst, snt, tid);
    mid_phase<4, 1>(rs, st, cst, snt, tid);
    mid_phase<4, 2>(rs, st, cst, snt, tid);
    mid_phase<5, 0>(rs, st, cst, snt, tid);
    mid_phase<5, 1>(rs, st, cst, snt, tid);
    lds_io<5, 2, false>(rs, st, tid);
    run_gates<5, 2>(rs, cst, snt, tid);

    // expectations in-register: gout = e13/e12 (rows 13/12 of U^6);
    // layout (5,2) thread-base has no bits >=10 -> sign compile-time per register
    constexpr uint32_t f0 = mhv<5,2,0>(), f1 = mhv<5,2,1>(), f2 = mhv<5,2,2>(), f3 = mhv<5,2,3>();
    float e0 = 0.0f, e1 = 0.0f;
#pragma unroll
    for (uint32_t r = 0; r < 64; ++r) {
        const uint32_t M = mreg(r, f0, f1, f2, f3);
        const float v = rs[r];
        e0 = fmaf(v, ((M >> 13) & 1u) ? -v : v, e0);
        e1 = fmaf(v, ((M >> 12) & 1u) ? -v : v, e1);
    }
#pragma unroll
    for (int off = 32; off > 0; off >>= 1) {
        e0 += __shfl_down(e0, off);
        e1 += __shfl_down(e1, off);
    }
    const int wid = tid >> 6, lane = tid & 63;
    if (lane == 0) { red0[wid] = e0; red1[wid] = e1; }
    __syncthreads();
    if (tid == 0) {
        out[b * 2 + 0] = red0[0] + red0[1] + red0[2] + red0[3];
        out[b * 2 + 1] = red1[0] + red1[1] + red1[2] + red1[3];
    }
}

extern "C" void kernel_launch(void* const* d_in, const int* in_sizes, int n_in,
                              void* d_out, int out_size, void* d_ws, size_t ws_size,
                              hipStream_t stream) {
    const float* x = (const float*)d_in[0];   // (1024, 14) f32
    const float* w = (const float*)d_in[1];   // (6, 14) f32
    float* out = (float*)d_out;               // (1024, 2) f32
    float* ws = (float*)d_ws;                 // [0..27] min/scale, [32..101] cos, [112..181] sin

    qs_norm_kernel<<<NQ, 256, 0, stream>>>(x, w, ws);
    qs_main_kernel<<<NBATCH, BLOCK, 0, stream>>>(x, w, ws, ws + 32, ws + 112, out);
}